// Round 9
// baseline (322.685 us; speedup 1.0000x reference)
//
#include <hip/hip_runtime.h>

// VQ pairwise L2, single fused kernel: out[n,k] = ||X[n,:] - E[k,:]||.
// N=65536, K=1024, D=64. One 128x128 output tile per block (4 waves).
//
// R8/R9 (resubmit after infra failure): BARRIER-FREE / LDS-FREE. D=64 means
// an MFMA fragment is 16B of one row -> build fragments DIRECTLY from
// global fp32 (2x float4 + in-reg RNE fp32->bf16, numerically identical to
// the old LDS-staged path; X/E tiles are L2-resident). Row norms via
// shfl_xor(16/32) cross-quad reduction (lane's fragment rows == the rows
// it needs); E-col norms redistributed with 16 one-time shuffles. Zero LDS,
// zero __syncthreads: waves free-run, strip i+1 loads pipeline under strip
// i MFMA+stores, stores spread over the whole kernel lifetime (no
// phase-beating). E fragments + norms built once per block, reused across
// 4 X-strips.
//
// Epilogue: SWAPPED-operand MFMA (E as A-operand) -> lane's 4 acc regs =
// 4 consecutive output cols -> 16B cached global_store_dwordx4 (R4 result:
// cached beats nontemporal; R6: linear-store re-layout is null).
//
// XCD swizzle (T1): 4096 blocks, 8 XCDs; contiguous tile chunk per XCD;
// the 8 bx-siblings of an X row-panel run adjacently on one XCD.

typedef __attribute__((ext_vector_type(8))) short short8;    // 8 bf16 = 4 VGPR
typedef __attribute__((ext_vector_type(4))) float floatx4;   // MFMA C/D + stores

#define N_ROWS 65536

__device__ __forceinline__ unsigned short f2bf(float f) {
    unsigned int u = __float_as_uint(f);
    u += 0x7FFFu + ((u >> 16) & 1u);     // round-to-nearest-even
    return (unsigned short)(u >> 16);
}
__device__ __forceinline__ float bf2f(unsigned short h) {
    return __uint_as_float(((unsigned int)h) << 16);
}

// convert 8 fp32 -> bf16 fragment half, accumulate sum of squares of the
// ROUNDED values (matches the reference-passing numerics of R4-R7).
__device__ __forceinline__ void cvt8(float4 lo, float4 hi, short8* frag, float* s) {
    const float f[8] = {lo.x, lo.y, lo.z, lo.w, hi.x, hi.y, hi.z, hi.w};
    #pragma unroll
    for (int k = 0; k < 8; ++k) {
        const unsigned short h = f2bf(f[k]);
        const float r = bf2f(h);
        *s = fmaf(r, r, *s);
        (*frag)[k] = (short)h;
    }
}

__global__ __launch_bounds__(256, 4) void vq_fused(const float* __restrict__ X,
                                                   const float* __restrict__ E,
                                                   float* __restrict__ out,
                                                   int Ktot) {
    const int tid = threadIdx.x;

    // ---- XCD-aware tile swizzle (bijective: 4096 % 8 == 0) ----
    const int nxb = Ktot >> 7;                 // tiles along K (8)
    const int cpx = gridDim.x >> 3;            // tiles per XCD (512)
    const int bid = blockIdx.x;
    const int swz = (bid & 7) * cpx + (bid >> 3);
    const int bx = swz % nxb;
    const int by = swz / nxb;
    const size_t m0 = (size_t)by * 128;
    const int n0 = bx * 128;

    // ---- per-wave geometry ----
    const int w = tid >> 6;
    const int lane = tid & 63;
    const int quad = lane >> 4;
    const int l16 = lane & 15;
    const int wm = (w >> 1) * 64;              // wave's 64-row half of tile
    const int wn = (w & 1) * 64;               // wave's 64-col half of tile

    // ---- E fragments + col norms, direct from global (once per block) ----
    short8 b0[4], b1[4];
    floatx4 eq[4];                             // eq[j][r] = ||E[wn+j*16+quad*4+r]||^2
    {
        float en[4];
        #pragma unroll
        for (int t = 0; t < 4; ++t) {
            const float* er = E + (size_t)(n0 + wn + t * 16 + l16) * 64 + quad * 8;
            const float4 e0 = *(const float4*)er;
            const float4 e1 = *(const float4*)(er + 4);
            const float4 e2 = *(const float4*)(er + 32);
            const float4 e3 = *(const float4*)(er + 36);
            float s = 0.f;
            cvt8(e0, e1, &b0[t], &s);
            cvt8(e2, e3, &b1[t], &s);
            s += __shfl_xor(s, 16, 64);        // sum across quads (cols 0..63)
            s += __shfl_xor(s, 32, 64);
            en[t] = s;                         // norm of E row wn+t*16+l16
        }
        #pragma unroll
        for (int j = 0; j < 4; ++j)
            #pragma unroll
            for (int r = 0; r < 4; ++r)
                eq[j][r] = __shfl(en[j], quad * 4 + r, 64);
    }

    // ---- 4 X-strips: load+convert -> norm -> MFMA -> store, no barriers ----
    #pragma unroll
    for (int i = 0; i < 4; ++i) {
        const int orow = wm + i * 16 + l16;    // this lane's output row
        const float* xr = X + (m0 + orow) * 64 + quad * 8;
        const float4 x0 = *(const float4*)xr;
        const float4 x1 = *(const float4*)(xr + 4);
        const float4 x2 = *(const float4*)(xr + 32);
        const float4 x3 = *(const float4*)(xr + 36);
        short8 a0, a1;
        float s = 0.f;
        cvt8(x0, x1, &a0, &s);
        cvt8(x2, x3, &a1, &s);
        s += __shfl_xor(s, 16, 64);            // full ||X[orow]||^2 in every lane
        s += __shfl_xor(s, 32, 64);
        const float xq = s;

        // SWAPPED operands: C/D col (l16) = output ROW, row (quad*4+r) = COLUMN.
        floatx4 acc[4];
        #pragma unroll
        for (int j = 0; j < 4; ++j) {
            acc[j] = __builtin_amdgcn_mfma_f32_16x16x32_bf16(
                b0[j], a0, (floatx4){0.f, 0.f, 0.f, 0.f}, 0, 0, 0);
            acc[j] = __builtin_amdgcn_mfma_f32_16x16x32_bf16(
                b1[j], a1, acc[j], 0, 0, 0);
        }

        float* op = out + (m0 + orow) * (size_t)Ktot + n0;
        #pragma unroll
        for (int j = 0; j < 4; ++j) {
            const int ncol0 = wn + j * 16 + quad * 4;   // 16B-aligned col base
            const floatx4 c = acc[j];
            const floatx4 e = eq[j];
            floatx4 o;
            #pragma unroll
            for (int r = 0; r < 4; ++r)
                o[r] = __builtin_amdgcn_sqrtf(fmaxf(xq + e[r] - 2.0f * c[r], 0.0f));
            *(floatx4*)(op + ncol0) = o;       // cached global_store_dwordx4
        }
    }
}

extern "C" void kernel_launch(void* const* d_in, const int* in_sizes, int n_in,
                              void* d_out, int out_size, void* d_ws, size_t ws_size,
                              hipStream_t stream) {
    const float* X = (const float*)d_in[0];
    const float* E = (const float*)d_in[1];
    float* out = (float*)d_out;
    const int K = in_sizes[1] / 64;   // 1024

    const int tiles = (N_ROWS / 128) * (K / 128);   // 4096
    vq_fused<<<dim3(tiles), dim3(256), 0, stream>>>(X, E, out, K);
}

// Round 10
// 294.762 us; speedup vs baseline: 1.0947x; 1.0947x over previous
//
#include <hip/hip_runtime.h>

// VQ pairwise L2: out[n,k] = ||X[n,:] - E[k,:]||. N=65536 K=1024 D=64.
//
// R10: PERSISTENT ROW-PANEL BLOCKS. One block per 128-row X panel
// (grid=512, 2 blocks/CU), looping over all 8 E col-tiles:
//  - X panel staged once: coalesced float4 loads -> in-reg RNE fp32->bf16
//    -> padded LDS (LSTR=72) + xsq; X fragments then hoisted to registers
//    (32 VGPR) and LDS_X is dead.
//  - E tiles streamed with T14 async split: iteration j reads E frags from
//    LDS, ISSUES coalesced E-tile j+1 loads into registers (in flight under
//    the whole compute+store phase), computes 4 strips (8 MFMA each,
//    swapped operands) storing each strip immediately (16B cached
//    global_store_dwordx4), then barrier -> convert+LDS-write E j+1 ->
//    barrier. Store pipe ~95% duty cycle; store-free prologue happens
//    2x/CU instead of 16x/CU (R7).
// R9 lesson: direct-from-global MFMA fragment gathers are uncoalesced
// (64x16B scatter per instruction) — all global loads here are dense
// wave-coalesced; fragments only ever come from LDS.
//
// XCD swizzle (T1, bijective 512%8==0): contiguous panel chunk per XCD.

typedef __attribute__((ext_vector_type(8))) short short8;    // 8 bf16 = 4 VGPR
typedef __attribute__((ext_vector_type(4))) float floatx4;   // MFMA C/D + stores

#define LSTR 72          // padded LDS row stride in bf16 elems (144 B)
#define N_ROWS 65536

__device__ __forceinline__ unsigned short f2bf(float f) {
    unsigned int u = __float_as_uint(f);
    u += 0x7FFFu + ((u >> 16) & 1u);     // round-to-nearest-even
    return (unsigned short)(u >> 16);
}
__device__ __forceinline__ float bf2f(unsigned short h) {
    return __uint_as_float(((unsigned int)h) << 16);
}

__global__ __launch_bounds__(256, 2) void vq_fused(const float* __restrict__ X,
                                                   const float* __restrict__ E,
                                                   float* __restrict__ out,
                                                   int Ktot) {
    __shared__ alignas(16) unsigned short ldsX[128 * LSTR];   // 18432 B
    __shared__ alignas(16) unsigned short ldsE[128 * LSTR];   // 18432 B
    __shared__ alignas(16) float s_xsq[128];
    __shared__ alignas(16) float s_esq[128];

    const int tid = threadIdx.x;

    // ---- XCD-aware panel swizzle (bijective: 512 % 8 == 0) ----
    const int cpx = gridDim.x >> 3;            // panels per XCD (64)
    const int bid = blockIdx.x;
    const size_t m0 = (size_t)((bid & 7) * cpx + (bid >> 3)) * 128;

    // staging geometry: 8 threads/row, 8 floats (2x float4) per thread
    const int srow = tid >> 3;                 // 0..31 (+32 per pass)
    const int sc8 = (tid & 7) * 8;

    // ---- prologue: stage X panel and E tile 0 (all loads issued first) ----
    float4 vx[4][2], ve[4][2];
    #pragma unroll
    for (int it = 0; it < 4; ++it) {
        const int row = it * 32 + srow;
        const float* p = X + (m0 + row) * 64 + sc8;
        vx[it][0] = *(const float4*)p;
        vx[it][1] = *(const float4*)(p + 4);
        const float* q = E + (size_t)row * 64 + sc8;   // tile 0: rows 0..127
        ve[it][0] = *(const float4*)q;
        ve[it][1] = *(const float4*)(q + 4);
    }
    #pragma unroll
    for (int half = 0; half < 2; ++half) {
        unsigned short* dst = half ? ldsE : ldsX;
        float* sq = half ? s_esq : s_xsq;
        #pragma unroll
        for (int it = 0; it < 4; ++it) {
            const int row = it * 32 + srow;
            const float* f = half ? (const float*)&ve[it][0] : (const float*)&vx[it][0];
            float s = 0.f;
            short8 pk;
            #pragma unroll
            for (int j = 0; j < 8; ++j) {
                const unsigned short h = f2bf(f[j]);
                const float r = bf2f(h);
                s = fmaf(r, r, s);          // norm from ROUNDED value
                pk[j] = (short)h;
            }
            *(short8*)&dst[row * LSTR + sc8] = pk;
            s += __shfl_down(s, 4, 8);
            s += __shfl_down(s, 2, 8);
            s += __shfl_down(s, 1, 8);
            if ((tid & 7) == 0) sq[row] = s;
        }
    }
    __syncthreads();

    // ---- per-wave geometry ----
    const int w = tid >> 6;
    const int lane = tid & 63;
    const int quad = lane >> 4;
    const int l16 = lane & 15;
    const int wm = (w >> 1) * 64;              // wave's 64-row half of panel
    const int wn = (w & 1) * 64;               // wave's 64-col half of tile

    // ---- hoist X fragments + row norms to registers (LDS_X dead after) ----
    short8 xa0[4], xa1[4];
    float xqv[4];
    #pragma unroll
    for (int i = 0; i < 4; ++i) {
        const int ar = wm + i * 16 + l16;
        xa0[i] = *(const short8*)&ldsX[ar * LSTR + quad * 8];
        xa1[i] = *(const short8*)&ldsX[ar * LSTR + 32 + quad * 8];
        xqv[i] = s_xsq[ar];
    }

    // ---- stream 8 E col-tiles ----
    for (int jt = 0; jt < 8; ++jt) {
        const int n0 = jt * 128;

        // E fragments + col norms for THIS tile (from LDS)
        short8 b0[4], b1[4];
        floatx4 eqv[4];
        #pragma unroll
        for (int t = 0; t < 4; ++t) {
            const int br = wn + t * 16 + l16;
            b0[t] = *(const short8*)&ldsE[br * LSTR + quad * 8];
            b1[t] = *(const short8*)&ldsE[br * LSTR + 32 + quad * 8];
            eqv[t] = *(const floatx4*)&s_esq[wn + t * 16 + quad * 4];
        }

        // issue NEXT tile's coalesced loads (in flight under compute+stores)
        float4 pf[4][2];
        if (jt < 7) {
            const float* gEn = E + (size_t)(n0 + 128) * 64;
            #pragma unroll
            for (int it = 0; it < 4; ++it) {
                const float* q = gEn + (it * 32 + srow) * 64 + sc8;
                pf[it][0] = *(const float4*)q;
                pf[it][1] = *(const float4*)(q + 4);
            }
        }

        // compute 4 strips, store each immediately
        #pragma unroll
        for (int i = 0; i < 4; ++i) {
            floatx4 acc[4];
            #pragma unroll
            for (int j = 0; j < 4; ++j) {
                acc[j] = __builtin_amdgcn_mfma_f32_16x16x32_bf16(
                    b0[j], xa0[i], (floatx4){0.f, 0.f, 0.f, 0.f}, 0, 0, 0);
                acc[j] = __builtin_amdgcn_mfma_f32_16x16x32_bf16(
                    b1[j], xa1[i], acc[j], 0, 0, 0);
            }
            const int orow = wm + i * 16 + l16;
            const float xq = xqv[i];
            float* op = out + (m0 + orow) * (size_t)Ktot + n0;
            #pragma unroll
            for (int j = 0; j < 4; ++j) {
                const int ncol0 = wn + j * 16 + quad * 4;
                const floatx4 c = acc[j];
                const floatx4 e = eqv[j];
                floatx4 o;
                #pragma unroll
                for (int r = 0; r < 4; ++r)
                    o[r] = __builtin_amdgcn_sqrtf(fmaxf(xq + e[r] - 2.0f * c[r], 0.0f));
                *(floatx4*)(op + ncol0) = o;   // cached global_store_dwordx4
            }
        }

        // rotate E tile: convert prefetched regs -> LDS (double barrier)
        if (jt < 7) {
            __syncthreads();                   // all waves done reading ldsE
            #pragma unroll
            for (int it = 0; it < 4; ++it) {
                const int row = it * 32 + srow;
                const float* f = (const float*)&pf[it][0];
                float s = 0.f;
                short8 pk;
                #pragma unroll
                for (int j = 0; j < 8; ++j) {
                    const unsigned short h = f2bf(f[j]);
                    const float r = bf2f(h);
                    s = fmaf(r, r, s);
                    pk[j] = (short)h;
                }
                *(short8*)&ldsE[row * LSTR + sc8] = pk;
                s += __shfl_down(s, 4, 8);
                s += __shfl_down(s, 2, 8);
                s += __shfl_down(s, 1, 8);
                if ((tid & 7) == 0) s_esq[row] = s;
            }
            __syncthreads();                   // next tile ready
        }
    }
}

extern "C" void kernel_launch(void* const* d_in, const int* in_sizes, int n_in,
                              void* d_out, int out_size, void* d_ws, size_t ws_size,
                              hipStream_t stream) {
    const float* X = (const float*)d_in[0];
    const float* E = (const float*)d_in[1];
    float* out = (float*)d_out;
    const int K = in_sizes[1] / 64;   // 1024

    vq_fused<<<dim3(N_ROWS / 128), dim3(256), 0, stream>>>(X, E, out, K);
}